// Round 4
// baseline (485.755 us; speedup 1.0000x reference)
//
#include <hip/hip_runtime.h>

#define T_LEN 120000
#define LBLK 160          // samples per scan block (divides 40000 and 120000)
#define PBLK 750          // number of scan blocks
#define CCH 32            // matmul chunk length in t
#define NCHUNK (LBLK / CCH)
#define BATCH 4
#define K0 250            // first valid block (t = 40000)
#define NKV 250           // valid blocks (t in [40000, 80000))
#define IB_LO 250         // ibuf stores block states for k in [250, 500]
#define IB_HI 500
#define DENOM 20480000.0  // 2 * 4 * 64 * 40000 (each |diff| counted twice)
#define YSTRIDE 132       // 128 channels + 4 pad words

__device__ __forceinline__ float fast_tanh(float x) {
  float e = __expf(2.0f * x);
  return 1.0f - 2.0f / (e + 1.0f);
}

// Canonicalize coefficients to double regardless of how the harness stored
// the reference's float64 arrays (f64 kept, or downcast to f32).
__global__ __launch_bounds__(64) void canon_coeffs(
    const void* a1p, const void* a2p, const void* b0p,
    double* ca1, double* ca2, double* cb0, double* wsum)
{
  __shared__ int isf64;
  if (threadIdx.x == 0) {
    double probe = *(const double*)a2p;
    isf64 = (probe > 0.9 && probe < 1.0) ? 1 : 0;
    *wsum = 0.0;
  }
  __syncthreads();
  int ch = threadIdx.x;
  if (isf64) {
    ca1[ch] = ((const double*)a1p)[ch];
    ca2[ch] = ((const double*)a2p)[ch];
    cb0[ch] = ((const double*)b0p)[ch];
  } else {
    ca1[ch] = (double)((const float*)a1p)[ch];
    ca2[ch] = (double)((const float*)a2p)[ch];
    cb0[ch] = (double)((const float*)b0p)[ch];
  }
}

// Pass 1: per (row, block) forced response with zero initial state.
// rows r: r = i*8 + d*4 + b  (i: 0=pred 1=target, d: 0=fwd 1=bwd, b: batch)
__global__ __launch_bounds__(64) void pass1(
    const float* __restrict__ pred, const float* __restrict__ tgt,
    const double* __restrict__ a1, const double* __restrict__ a2,
    const double* __restrict__ b0, double* __restrict__ fbuf)
{
  int k = blockIdx.x, r = blockIdx.y;
  int i = r >> 3, d = (r >> 2) & 1, b = r & 3;
  const float* sig = (i ? tgt : pred) + b * T_LEN;
  __shared__ float xs[LBLK];
  int base = k * LBLK;
  for (int j = threadIdx.x; j < LBLK; j += 64)
    xs[j] = d ? sig[T_LEN - 1 - (base + j)] : sig[base + j];
  __syncthreads();
  int ch = threadIdx.x;
  double A1 = a1[ch], A2 = a2[ch], B0 = b0[ch];
  double y1 = 0.0, y2 = 0.0;
  for (int j = 0; j < LBLK; ++j) {
    double y = fma(-A1, y1, fma(-A2, y2, B0 * (double)xs[j]));
    y2 = y1; y1 = y;
  }
  int s = r * 64 + ch;
  ((double2*)fbuf)[(size_t)k * 1024 + s] = make_double2(y1, y2);
}

// Pass 2: serial block-scan: v <- A^L v + f_k; store v only for needed blocks.
__global__ __launch_bounds__(256) void pass2(
    const double* __restrict__ a1, const double* __restrict__ a2,
    const double* __restrict__ fbuf, double* __restrict__ ibuf)
{
  int s = blockIdx.x * 256 + threadIdx.x; // scan id 0..1023
  int ch = s & 63;
  double A1 = a1[ch], A2 = a2[ch];
  // A^L by repeated squaring; A = [[-a1,-a2],[1,0]]
  double m00 = -A1, m01 = -A2, m10 = 1.0, m11 = 0.0;
  double r00 = 1.0, r01 = 0.0, r10 = 0.0, r11 = 1.0;
  int e = LBLK;
  while (e) {
    if (e & 1) {
      double t00 = r00 * m00 + r01 * m10, t01 = r00 * m01 + r01 * m11;
      double t10 = r10 * m00 + r11 * m10, t11 = r10 * m01 + r11 * m11;
      r00 = t00; r01 = t01; r10 = t10; r11 = t11;
    }
    e >>= 1;
    if (e) {
      double t00 = m00 * m00 + m01 * m10, t01 = m00 * m01 + m01 * m11;
      double t10 = m10 * m00 + m11 * m10, t11 = m10 * m01 + m11 * m11;
      m00 = t00; m01 = t01; m10 = t10; m11 = t11;
    }
  }
  const double2* fb = (const double2*)fbuf;
  double2* ib = (double2*)ibuf;
  double y1 = 0.0, y2 = 0.0;
  double2 f = fb[s]; // k = 0
  for (int k = 0; k < PBLK; ++k) {
    double2 fn = (k + 1 < PBLK) ? fb[(size_t)(k + 1) * 1024 + s]
                                : make_double2(0.0, 0.0);
    if (k >= IB_LO && k <= IB_HI)
      ib[(size_t)(k - IB_LO) * 1024 + s] = make_double2(y1, y2);
    double n1 = r00 * y1 + r01 * y2 + f.x;
    double n2 = r10 * y1 + r11 * y2 + f.y;
    y1 = n1; y2 = n2; f = fn;
  }
}

// Pass 3: per (valid block k, batch b): reconstruct states for all 128
// channels (64 fwd + 64 bwd), fused W@Y matvec + tanh + |diff| reduce.
// Matmul: lanes = 64 columns (32 t x 2 inputs), each wave sweeps a
// wave-uniform 16-output slice so W reads are scalar (s_load) broadcasts.
__global__ __launch_bounds__(256, 4) void pass3(
    const float* __restrict__ pred, const float* __restrict__ tgt,
    const double* __restrict__ a1, const double* __restrict__ a2,
    const double* __restrict__ b0, const float* __restrict__ W,
    const double* __restrict__ ibuf, double* __restrict__ wsum)
{
  int k = K0 + blockIdx.x;
  int b = blockIdx.y;
  int tid = threadIdx.x;
  __shared__ __align__(16) float ys[64 * YSTRIDE]; // [col(t,i)][128ch + pad]
  __shared__ float xs[2][CCH * NCHUNK];
  __shared__ float red[4];

  // stage x for this block
  for (int idx = tid; idx < 2 * LBLK; idx += 256) {
    int ii = idx / LBLK, j = idx - ii * LBLK;
    const float* sig = (ii ? tgt : pred) + b * T_LEN;
    xs[ii][j] = sig[k * LBLK + j];
  }

  int g = tid >> 6;                 // wave id (recurrence role: i,d)
  int gu = __builtin_amdgcn_readfirstlane(g);  // provably wave-uniform
  int obase = gu * 16;              // matmul: this wave's output slice
  int i = g >> 1, d = g & 1, ch = tid & 63;
  int col = tid & 63;               // matmul: lane's column (i*32 + t)
  int s = (i * 8 + d * 4 + b) * 64 + ch;
  double A1 = a1[ch], A2 = a2[ch], B0 = b0[ch];
  double invA2 = 1.0 / A2;
  double st0, st1;
  if (d == 0) {
    double2 v = ((const double2*)ibuf)[(size_t)(k - IB_LO) * 1024 + s];
    st0 = v.x; st1 = v.y;   // (y[kL-1], y[kL-2])
  } else {
    // bwd pre-state for this t-range: ibuf[PBLK-k] -> index 500-k
    double2 v = ((const double2*)ibuf)[(size_t)(IB_HI - k) * 1024 + s];
    st0 = v.x; st1 = v.y;   // (y_bwd at t=kL, y_bwd at t=kL+1)
  }
  __syncthreads();

  float loss = 0.0f;
  for (int cc = 0; cc < NCHUNK; ++cc) {
    // ---- recurrence phase (wave-uniform direction) ----
    if (d == 0) {
      #pragma unroll
      for (int tt = 0; tt < CCH; ++tt) {
        double x = (double)xs[i][cc * CCH + tt];
        double y = fma(-A1, st0, fma(-A2, st1, B0 * x));
        ys[(i * CCH + tt) * YSTRIDE + ch] = (float)y;
        st1 = st0; st0 = y;
      }
    } else {
      #pragma unroll
      for (int tt = 0; tt < CCH; ++tt) {
        double x = (double)xs[i][cc * CCH + tt];
        ys[(i * CCH + tt) * YSTRIDE + 64 + ch] = (float)st0;
        double ym2 = (fma(-A1, st1, B0 * x) - st0) * invA2;
        st0 = st1; st1 = ym2;
      }
    }
    __syncthreads();

    // ---- matmul phase: z[obase..obase+16) for this lane's column ----
    float acc[16];
    #pragma unroll
    for (int oo = 0; oo < 16; ++oo) acc[oo] = 0.0f;
    for (int q = 0; q < 4; ++q) {   // quarter of the 128-channel dot
      float4 ya[8];
      #pragma unroll
      for (int c4 = 0; c4 < 8; ++c4)
        ya[c4] = *(const float4*)&ys[col * YSTRIDE + q * 32 + c4 * 4];
      #pragma unroll
      for (int oo = 0; oo < 16; ++oo) {
        const float* wr = W + (obase + oo) * 128 + q * 32; // wave-uniform
        float a = acc[oo];
        #pragma unroll
        for (int c4 = 0; c4 < 8; ++c4) {
          a = fmaf(wr[c4 * 4 + 0], ya[c4].x, a);
          a = fmaf(wr[c4 * 4 + 1], ya[c4].y, a);
          a = fmaf(wr[c4 * 4 + 2], ya[c4].z, a);
          a = fmaf(wr[c4 * 4 + 3], ya[c4].w, a);
        }
        acc[oo] = a;
      }
    }
    // tanh + pred/target pairing: partner lane = col ^ 32 (other input)
    float l = 0.0f;
    #pragma unroll
    for (int oo = 0; oo < 16; ++oo) {
      float v = fast_tanh(acc[oo]);
      float p = __shfl_xor(v, 32);
      l += fabsf(v - p);
    }
    loss += l;
    __syncthreads();
  }

  // block reduction -> one double atomic per workgroup
  #pragma unroll
  for (int off = 32; off > 0; off >>= 1) loss += __shfl_down(loss, off);
  if ((tid & 63) == 0) red[tid >> 6] = loss;
  __syncthreads();
  if (tid == 0) atomicAdd(wsum, (double)(red[0] + red[1] + red[2] + red[3]));
}

__global__ void finalize(const double* __restrict__ wsum, float* __restrict__ out) {
  out[0] = (float)(wsum[0] / DENOM);
}

extern "C" void kernel_launch(void* const* d_in, const int* in_sizes, int n_in,
                              void* d_out, int out_size, void* d_ws, size_t ws_size,
                              hipStream_t stream) {
  const float* pred = (const float*)d_in[0];
  const float* tgt  = (const float*)d_in[1];
  const float* W    = (const float*)d_in[5];
  float* out = (float*)d_out;

  double* base = (double*)d_ws;
  double* wsum = base;                      // [1] (pad to 8)
  double* ca1  = base + 8;                  // [64]
  double* ca2  = base + 72;                 // [64]
  double* cb0  = base + 136;                // [64]
  double* fbuf = base + 200;                // [PBLK][1024][2]
  double* ibuf = fbuf + (size_t)PBLK * 1024 * 2;  // [251][1024][2]

  canon_coeffs<<<1, 64, 0, stream>>>(d_in[2], d_in[3], d_in[4], ca1, ca2, cb0, wsum);
  pass1<<<dim3(PBLK, 16), 64, 0, stream>>>(pred, tgt, ca1, ca2, cb0, fbuf);
  pass2<<<dim3(4), 256, 0, stream>>>(ca1, ca2, fbuf, ibuf);
  pass3<<<dim3(NKV, BATCH), 256, 0, stream>>>(pred, tgt, ca1, ca2, cb0, W, ibuf, wsum);
  finalize<<<1, 1, 0, stream>>>(wsum, out);
}

// Round 5
// 167.762 us; speedup vs baseline: 2.8955x; 2.8955x over previous
//
#include <hip/hip_runtime.h>

#define T_LEN 120000
#define LBLK 160          // samples per scan block (divides 40000)
#define PBLK 750          // number of scan blocks
#define SEG_LEN 25        // blocks per scan segment
#define NSEG 30           // segments (SEG_LEN*NSEG == PBLK)
#define CCH 32            // t-steps per pass3 chunk
#define NCHUNK (LBLK / CCH)
#define BATCH 4
#define K0 250            // first valid block (t = 40000)
#define NKV 250           // valid blocks (t in [40000, 80000))
#define IB_LO 250         // ibuf holds block states k in [250, 500]
#define IB_HI 500
#define DENOM 20480000.0  // 2 * 4 * 64 * 40000 (each |diff| counted twice)
#define YSTR 136          // halves per ys row: 128 ch + 8 pad

typedef _Float16 half8 __attribute__((ext_vector_type(8)));
typedef float f32x4 __attribute__((ext_vector_type(4)));

__device__ __forceinline__ float fast_tanh(float x) {
  float e = __expf(2.0f * x);
  return 1.0f - 2.0f / (e + 1.0f);
}

// state-transition matrix A^e for A = [[-a1,-a2],[1,0]] by repeated squaring
__device__ __forceinline__ void mat_pow(double A1, double A2, int e,
                                        double& r00, double& r01,
                                        double& r10, double& r11) {
  double m00 = -A1, m01 = -A2, m10 = 1.0, m11 = 0.0;
  r00 = 1.0; r01 = 0.0; r10 = 0.0; r11 = 1.0;
  while (e) {
    if (e & 1) {
      double t00 = r00 * m00 + r01 * m10, t01 = r00 * m01 + r01 * m11;
      double t10 = r10 * m00 + r11 * m10, t11 = r10 * m01 + r11 * m11;
      r00 = t00; r01 = t01; r10 = t10; r11 = t11;
    }
    e >>= 1;
    if (e) {
      double t00 = m00 * m00 + m01 * m10, t01 = m00 * m01 + m01 * m11;
      double t10 = m10 * m00 + m11 * m10, t11 = m10 * m01 + m11 * m11;
      m00 = t00; m01 = t01; m10 = t10; m11 = t11;
    }
  }
}

// Canonicalize coefficients to double regardless of how the harness stored
// the reference's float64 arrays (f64 kept, or downcast to f32).
__global__ __launch_bounds__(64) void canon_coeffs(
    const void* a1p, const void* a2p, const void* b0p,
    double* ca1, double* ca2, double* cb0, double* wsum)
{
  __shared__ int isf64;
  if (threadIdx.x == 0) {
    double probe = *(const double*)a2p;
    isf64 = (probe > 0.9 && probe < 1.0) ? 1 : 0;
    *wsum = 0.0;
  }
  __syncthreads();
  int ch = threadIdx.x;
  if (isf64) {
    ca1[ch] = ((const double*)a1p)[ch];
    ca2[ch] = ((const double*)a2p)[ch];
    cb0[ch] = ((const double*)b0p)[ch];
  } else {
    ca1[ch] = (double)((const float*)a1p)[ch];
    ca2[ch] = (double)((const float*)a2p)[ch];
    cb0[ch] = (double)((const float*)b0p)[ch];
  }
}

// Convert W (f32 [64][128]) to f16 once; pass3 reads A-fragments from it.
__global__ __launch_bounds__(256) void cvtW(const float* __restrict__ W,
                                            _Float16* __restrict__ Wh) {
  int idx = blockIdx.x * 256 + threadIdx.x;
  Wh[idx] = (_Float16)W[idx];
}

// Pass 1: per (row, block) forced response with zero initial state.
// rows r: r = i*8 + d*4 + b  (i: 0=pred 1=target, d: 0=fwd 1=bwd, b: batch)
__global__ __launch_bounds__(64) void pass1(
    const float* __restrict__ pred, const float* __restrict__ tgt,
    const double* __restrict__ a1, const double* __restrict__ a2,
    const double* __restrict__ b0, double* __restrict__ fbuf)
{
  int k = blockIdx.x, r = blockIdx.y;
  int i = r >> 3, d = (r >> 2) & 1, b = r & 3;
  const float* sig = (i ? tgt : pred) + b * T_LEN;
  __shared__ float xs[LBLK];
  int base = k * LBLK;
  for (int j = threadIdx.x; j < LBLK; j += 64)
    xs[j] = d ? sig[T_LEN - 1 - (base + j)] : sig[base + j];
  __syncthreads();
  int ch = threadIdx.x;
  double A1 = a1[ch], A2 = a2[ch], B0 = b0[ch];
  double y1 = 0.0, y2 = 0.0;
  for (int j = 0; j < LBLK; ++j) {
    double y = fma(-A1, y1, fma(-A2, y2, B0 * (double)xs[j]));
    y2 = y1; y1 = y;
  }
  int s = r * 64 + ch;
  ((double2*)fbuf)[(size_t)k * 1024 + s] = make_double2(y1, y2);
}

// Pass 2a: per-segment aggregate (forced response of 25 blocks, zero init).
__global__ __launch_bounds__(64) void pass2a(
    const double* __restrict__ a1, const double* __restrict__ a2,
    const double* __restrict__ fbuf, double* __restrict__ sbuf)
{
  int seg = blockIdx.x >> 4;
  int s = ((blockIdx.x & 15) << 6) + threadIdx.x;
  int ch = s & 63;
  double r00, r01, r10, r11;
  mat_pow(a1[ch], a2[ch], LBLK, r00, r01, r10, r11);
  const double2* fb = (const double2*)fbuf;
  double y1 = 0.0, y2 = 0.0;
  for (int jj = 0; jj < SEG_LEN / 5; ++jj) {
    size_t kb = (size_t)(seg * SEG_LEN + jj * 5) * 1024 + s;
    double2 f0 = fb[kb], f1 = fb[kb + 1024], f2 = fb[kb + 2048],
            f3 = fb[kb + 3072], f4 = fb[kb + 4096];
    double n1, n2;
    n1 = r00*y1 + r01*y2 + f0.x; n2 = r10*y1 + r11*y2 + f0.y; y1=n1; y2=n2;
    n1 = r00*y1 + r01*y2 + f1.x; n2 = r10*y1 + r11*y2 + f1.y; y1=n1; y2=n2;
    n1 = r00*y1 + r01*y2 + f2.x; n2 = r10*y1 + r11*y2 + f2.y; y1=n1; y2=n2;
    n1 = r00*y1 + r01*y2 + f3.x; n2 = r10*y1 + r11*y2 + f3.y; y1=n1; y2=n2;
    n1 = r00*y1 + r01*y2 + f4.x; n2 = r10*y1 + r11*y2 + f4.y; y1=n1; y2=n2;
  }
  ((double2*)sbuf)[(size_t)seg * 1024 + s] = make_double2(y1, y2);
}

// Pass 2b: serial scan over the 30 segment aggregates -> segment-start states.
__global__ __launch_bounds__(256) void pass2b(
    const double* __restrict__ a1, const double* __restrict__ a2,
    const double* __restrict__ sbuf, double* __restrict__ tbuf)
{
  int s = blockIdx.x * 256 + threadIdx.x;
  int ch = s & 63;
  double r00, r01, r10, r11;
  mat_pow(a1[ch], a2[ch], LBLK * SEG_LEN, r00, r01, r10, r11);
  const double2* sb = (const double2*)sbuf;
  double2* tb = (double2*)tbuf;
  double y1 = 0.0, y2 = 0.0;
  for (int seg = 0; seg < NSEG; ++seg) {
    tb[(size_t)seg * 1024 + s] = make_double2(y1, y2);
    double2 f = sb[(size_t)seg * 1024 + s];
    double n1 = r00 * y1 + r01 * y2 + f.x;
    double n2 = r10 * y1 + r11 * y2 + f.y;
    y1 = n1; y2 = n2;
  }
}

// Pass 2c: expand segments 10..20 into per-block states for k in [250,500].
__global__ __launch_bounds__(64) void pass2c(
    const double* __restrict__ a1, const double* __restrict__ a2,
    const double* __restrict__ fbuf, const double* __restrict__ tbuf,
    double* __restrict__ ibuf)
{
  int seg = 10 + (blockIdx.x >> 4);
  int s = ((blockIdx.x & 15) << 6) + threadIdx.x;
  int ch = s & 63;
  double r00, r01, r10, r11;
  mat_pow(a1[ch], a2[ch], LBLK, r00, r01, r10, r11);
  const double2* fb = (const double2*)fbuf;
  double2* ib = (double2*)ibuf;
  double2 v = ((const double2*)tbuf)[(size_t)seg * 1024 + s];
  double y1 = v.x, y2 = v.y;
  for (int j = 0; j < SEG_LEN; ++j) {
    int k = seg * SEG_LEN + j;
    if (k >= IB_LO && k <= IB_HI)
      ib[(size_t)(k - IB_LO) * 1024 + s] = make_double2(y1, y2);
    double2 f = fb[(size_t)k * 1024 + s];
    double n1 = r00 * y1 + r01 * y2 + f.x;
    double n2 = r10 * y1 + r11 * y2 + f.y;
    y1 = n1; y2 = n2;
  }
}

// Pass 3: per (valid block k, batch b): f64 recurrence reconstructs exact
// states -> f16 Y in LDS (B-fragment layout, col = 2t+input) -> MFMA
// 16x16x32_f16 computes z = W@Y -> tanh -> |pred - tgt| via shfl_xor(,1).
__global__ __launch_bounds__(256, 4) void pass3(
    const float* __restrict__ pred, const float* __restrict__ tgt,
    const double* __restrict__ a1, const double* __restrict__ a2,
    const double* __restrict__ b0, const _Float16* __restrict__ Wh,
    const double* __restrict__ ibuf, double* __restrict__ wsum)
{
  int k = K0 + blockIdx.x;
  int b = blockIdx.y;
  int tid = threadIdx.x;
  __shared__ __align__(16) _Float16 ys[64 * YSTR]; // [col(2t+i)][128ch+pad]
  __shared__ float xs[2][LBLK];
  __shared__ float red[4];

  // stage x for this block
  for (int idx = tid; idx < 2 * LBLK; idx += 256) {
    int ii = idx / LBLK, j = idx - ii * LBLK;
    const float* sig = (ii ? tgt : pred) + b * T_LEN;
    xs[ii][j] = sig[k * LBLK + j];
  }

  int g = tid >> 6;                       // wave id: g = i*2 + d
  int lane = tid & 63;
  int i = g >> 1, d = g & 1, ch = lane;
  int gu = __builtin_amdgcn_readfirstlane(g);
  int n0 = gu * 16;                       // wave's N-tile (16 cols = 8 t x 2)
  int lm = lane & 15;                     // m (A-row) / n (B-col) index
  int quad = lane >> 4;                   // k-quad within fragment

  int s = (i * 8 + d * 4 + b) * 64 + ch;
  double A1 = a1[ch], A2 = a2[ch], B0 = b0[ch];
  double invA2 = 1.0 / A2;
  double st0, st1;
  if (d == 0) {
    double2 v = ((const double2*)ibuf)[(size_t)(k - IB_LO) * 1024 + s];
    st0 = v.x; st1 = v.y;   // (y[kL-1], y[kL-2])
  } else {
    double2 v = ((const double2*)ibuf)[(size_t)(IB_HI - k) * 1024 + s];
    st0 = v.x; st1 = v.y;   // (y_bwd at t=kL, y_bwd at t=kL+1)
  }
  __syncthreads();

  float loss = 0.0f;
  for (int cc = 0; cc < NCHUNK; ++cc) {
    // ---- recurrence phase (wave-uniform direction) ----
    if (d == 0) {
      #pragma unroll
      for (int tt = 0; tt < CCH; ++tt) {
        double x = (double)xs[i][cc * CCH + tt];
        double y = fma(-A1, st0, fma(-A2, st1, B0 * x));
        ys[(2 * tt + i) * YSTR + ch] = (_Float16)y;
        st1 = st0; st0 = y;
      }
    } else {
      #pragma unroll
      for (int tt = 0; tt < CCH; ++tt) {
        double x = (double)xs[i][cc * CCH + tt];
        ys[(2 * tt + i) * YSTR + 64 + ch] = (_Float16)st0;
        double ym2 = (fma(-A1, st1, B0 * x) - st0) * invA2;
        st0 = st1; st1 = ym2;
      }
    }
    __syncthreads();

    // ---- MFMA phase: wave computes z[0..63][its 16 cols] ----
    // B-frag (k0): B[k0*32+quad*8+j][n0+lm] = ys[(n0+lm)*YSTR + k0*32+quad*8+j]
    const _Float16* yrow = &ys[(n0 + lm) * YSTR + quad * 8];
    half8 bf0 = *(const half8*)(yrow);
    half8 bf1 = *(const half8*)(yrow + 32);
    half8 bf2 = *(const half8*)(yrow + 64);
    half8 bf3 = *(const half8*)(yrow + 96);
    f32x4 c0 = {0,0,0,0}, c1 = {0,0,0,0}, c2 = {0,0,0,0}, c3 = {0,0,0,0};
    const _Float16* wrow = Wh + lm * 128 + quad * 8; // A[m][k] base for m0=0,k0=0
    #pragma unroll
    for (int m0 = 0; m0 < 4; ++m0) {
      const _Float16* wr = wrow + m0 * 16 * 128;
      half8 a0 = *(const half8*)(wr);
      half8 a1f = *(const half8*)(wr + 32);
      half8 a2f = *(const half8*)(wr + 64);
      half8 a3f = *(const half8*)(wr + 96);
      f32x4 c = (m0 == 0) ? c0 : (m0 == 1) ? c1 : (m0 == 2) ? c2 : c3;
      c = __builtin_amdgcn_mfma_f32_16x16x32_f16(a0, bf0, c, 0, 0, 0);
      c = __builtin_amdgcn_mfma_f32_16x16x32_f16(a1f, bf1, c, 0, 0, 0);
      c = __builtin_amdgcn_mfma_f32_16x16x32_f16(a2f, bf2, c, 0, 0, 0);
      c = __builtin_amdgcn_mfma_f32_16x16x32_f16(a3f, bf3, c, 0, 0, 0);
      if (m0 == 0) c0 = c; else if (m0 == 1) c1 = c;
      else if (m0 == 2) c2 = c; else c3 = c;
    }
    // epilogue: tanh + pred/tgt pairing (partner lane = lane^1, col = 2t+i)
    #pragma unroll
    for (int m0 = 0; m0 < 4; ++m0) {
      f32x4 c = (m0 == 0) ? c0 : (m0 == 1) ? c1 : (m0 == 2) ? c2 : c3;
      #pragma unroll
      for (int r = 0; r < 4; ++r) {
        float v = fast_tanh(c[r]);
        float p = __shfl_xor(v, 1);
        loss += fabsf(v - p);
      }
    }
    __syncthreads();
  }

  // block reduction -> one double atomic per workgroup
  #pragma unroll
  for (int off = 32; off > 0; off >>= 1) loss += __shfl_down(loss, off);
  if ((tid & 63) == 0) red[tid >> 6] = loss;
  __syncthreads();
  if (tid == 0) atomicAdd(wsum, (double)(red[0] + red[1] + red[2] + red[3]));
}

__global__ void finalize(const double* __restrict__ wsum, float* __restrict__ out) {
  out[0] = (float)(wsum[0] / DENOM);
}

extern "C" void kernel_launch(void* const* d_in, const int* in_sizes, int n_in,
                              void* d_out, int out_size, void* d_ws, size_t ws_size,
                              hipStream_t stream) {
  const float* pred = (const float*)d_in[0];
  const float* tgt  = (const float*)d_in[1];
  const float* W    = (const float*)d_in[5];
  float* out = (float*)d_out;

  double* base = (double*)d_ws;
  double* wsum = base;                              // [1] (pad to 8)
  double* ca1  = base + 8;                          // [64]
  double* ca2  = base + 72;                         // [64]
  double* cb0  = base + 136;                        // [64]
  _Float16* Wh = (_Float16*)(base + 200);           // [64*128] f16 (16 KB)
  double* fbuf = base + 2248;                       // [750][1024][2]
  double* ibuf = fbuf + (size_t)PBLK * 1024 * 2;    // [251][1024][2]
  double* sbuf = ibuf + (size_t)(IB_HI - IB_LO + 1) * 1024 * 2;  // [30][1024][2]
  double* tbuf = sbuf + (size_t)NSEG * 1024 * 2;    // [30][1024][2]

  canon_coeffs<<<1, 64, 0, stream>>>(d_in[2], d_in[3], d_in[4], ca1, ca2, cb0, wsum);
  cvtW<<<32, 256, 0, stream>>>(W, Wh);
  pass1<<<dim3(PBLK, 16), 64, 0, stream>>>(pred, tgt, ca1, ca2, cb0, fbuf);
  pass2a<<<NSEG * 16, 64, 0, stream>>>(ca1, ca2, fbuf, sbuf);
  pass2b<<<dim3(4), 256, 0, stream>>>(ca1, ca2, sbuf, tbuf);
  pass2c<<<11 * 16, 64, 0, stream>>>(ca1, ca2, fbuf, tbuf, ibuf);
  pass3<<<dim3(NKV, BATCH), 256, 0, stream>>>(pred, tgt, ca1, ca2, cb0, Wh, ibuf, wsum);
  finalize<<<1, 1, 0, stream>>>(wsum, out);
}

// Round 6
// 137.111 us; speedup vs baseline: 3.5428x; 1.2236x over previous
//
#include <hip/hip_runtime.h>

#define T_LEN 120000
#define LBLK 160          // samples per scan block (divides 40000)
#define PBLK 750          // number of scan blocks
#define SEG_LEN 25        // blocks per scan segment
#define NSEG 30           // segments (SEG_LEN*NSEG == PBLK)
#define CCH 32            // t-steps per pass3 chunk
#define NCHUNK (LBLK / CCH)
#define BATCH 4
#define K0 250            // first valid block (t = 40000)
#define NKV 250           // valid blocks (t in [40000, 80000))
#define IB_LO 250         // ibuf holds block states k in [250, 500]
#define IB_HI 500
#define DENOM 20480000.0  // 2 * 4 * 64 * 40000 (each |diff| counted twice)
#define YSTR 130          // halves per ys row: 128 ch + 2 pad (odd dword stride)

typedef _Float16 half8 __attribute__((ext_vector_type(8)));
typedef float f32x4 __attribute__((ext_vector_type(4)));

__device__ __forceinline__ float fast_tanh(float x) {
  float e = __expf(2.0f * x);
  return 1.0f - 2.0f / (e + 1.0f);
}

// state-transition matrix A^e for A = [[-a1,-a2],[1,0]] by repeated squaring
__device__ __forceinline__ void mat_pow(double A1, double A2, int e,
                                        double& r00, double& r01,
                                        double& r10, double& r11) {
  double m00 = -A1, m01 = -A2, m10 = 1.0, m11 = 0.0;
  r00 = 1.0; r01 = 0.0; r10 = 0.0; r11 = 1.0;
  while (e) {
    if (e & 1) {
      double t00 = r00 * m00 + r01 * m10, t01 = r00 * m01 + r01 * m11;
      double t10 = r10 * m00 + r11 * m10, t11 = r10 * m01 + r11 * m11;
      r00 = t00; r01 = t01; r10 = t10; r11 = t11;
    }
    e >>= 1;
    if (e) {
      double t00 = m00 * m00 + m01 * m10, t01 = m00 * m01 + m01 * m11;
      double t10 = m10 * m00 + m11 * m10, t11 = m10 * m01 + m11 * m11;
      m00 = t00; m01 = t01; m10 = t10; m11 = t11;
    }
  }
}

// Canonicalize coeffs (f64 scan copies + f32 fast copies), convert W to f16,
// zero the accumulator. Handles harness storing float64 inputs as f32 or f64.
__global__ __launch_bounds__(256) void canon(
    const void* a1p, const void* a2p, const void* b0p, const float* __restrict__ W,
    double* ca1, double* ca2, double* cb0, float* cf, _Float16* Wh, double* wsum)
{
  int tid = threadIdx.x;
  __shared__ int isf64;
  if (tid == 0) {
    double probe = *(const double*)a2p;
    isf64 = (probe > 0.9 && probe < 1.0) ? 1 : 0;
    *wsum = 0.0;
  }
  __syncthreads();
  if (tid < 64) {
    double A1, A2, B0;
    if (isf64) {
      A1 = ((const double*)a1p)[tid];
      A2 = ((const double*)a2p)[tid];
      B0 = ((const double*)b0p)[tid];
    } else {
      A1 = (double)((const float*)a1p)[tid];
      A2 = (double)((const float*)a2p)[tid];
      B0 = (double)((const float*)b0p)[tid];
    }
    ca1[tid] = A1; ca2[tid] = A2; cb0[tid] = B0;
    cf[tid] = (float)A1; cf[64 + tid] = (float)A2;
    cf[128 + tid] = (float)B0; cf[192 + tid] = (float)(1.0 / A2);
  }
  for (int idx = tid; idx < 64 * 128; idx += 256) Wh[idx] = (_Float16)W[idx];
}

// Pass 1: per (row, block) forced response with zero initial state, f32.
// (Re-based every LBLK steps by the f64 scan -> f32 error ~1e-7*160, safe.)
// rows r: r = i*8 + d*4 + b  (i: 0=pred 1=target, d: 0=fwd 1=bwd, b: batch)
__global__ __launch_bounds__(64) void pass1(
    const float* __restrict__ pred, const float* __restrict__ tgt,
    const float* __restrict__ cf, double* __restrict__ fbuf)
{
  int k = blockIdx.x, r = blockIdx.y;
  int i = r >> 3, d = (r >> 2) & 1, b = r & 3;
  const float* sig = (i ? tgt : pred) + b * T_LEN;
  __shared__ float xs[LBLK];
  int base = k * LBLK;
  for (int j = threadIdx.x; j < LBLK; j += 64)
    xs[j] = d ? sig[T_LEN - 1 - (base + j)] : sig[base + j];
  __syncthreads();
  int ch = threadIdx.x;
  float A1 = cf[ch], A2 = cf[64 + ch], B0 = cf[128 + ch];
  float y1 = 0.0f, y2 = 0.0f;
  for (int j = 0; j < LBLK; ++j) {
    float y = fmaf(-A1, y1, fmaf(-A2, y2, B0 * xs[j]));
    y2 = y1; y1 = y;
  }
  int s = r * 64 + ch;
  ((double2*)fbuf)[(size_t)k * 1024 + s] = make_double2((double)y1, (double)y2);
}

// Pass 2a: per-segment aggregate (forced response of 25 blocks, zero init), f64.
__global__ __launch_bounds__(64) void pass2a(
    const double* __restrict__ a1, const double* __restrict__ a2,
    const double* __restrict__ fbuf, double* __restrict__ sbuf)
{
  int seg = blockIdx.x >> 4;
  int s = ((blockIdx.x & 15) << 6) + threadIdx.x;
  int ch = s & 63;
  double r00, r01, r10, r11;
  mat_pow(a1[ch], a2[ch], LBLK, r00, r01, r10, r11);
  const double2* fb = (const double2*)fbuf;
  double y1 = 0.0, y2 = 0.0;
  for (int jj = 0; jj < SEG_LEN / 5; ++jj) {
    size_t kb = (size_t)(seg * SEG_LEN + jj * 5) * 1024 + s;
    double2 f0 = fb[kb], f1 = fb[kb + 1024], f2 = fb[kb + 2048],
            f3 = fb[kb + 3072], f4 = fb[kb + 4096];
    double n1, n2;
    n1 = r00*y1 + r01*y2 + f0.x; n2 = r10*y1 + r11*y2 + f0.y; y1=n1; y2=n2;
    n1 = r00*y1 + r01*y2 + f1.x; n2 = r10*y1 + r11*y2 + f1.y; y1=n1; y2=n2;
    n1 = r00*y1 + r01*y2 + f2.x; n2 = r10*y1 + r11*y2 + f2.y; y1=n1; y2=n2;
    n1 = r00*y1 + r01*y2 + f3.x; n2 = r10*y1 + r11*y2 + f3.y; y1=n1; y2=n2;
    n1 = r00*y1 + r01*y2 + f4.x; n2 = r10*y1 + r11*y2 + f4.y; y1=n1; y2=n2;
  }
  ((double2*)sbuf)[(size_t)seg * 1024 + s] = make_double2(y1, y2);
}

// Pass 2b: serial scan over the 30 segment aggregates -> segment-start states.
__global__ __launch_bounds__(256) void pass2b(
    const double* __restrict__ a1, const double* __restrict__ a2,
    const double* __restrict__ sbuf, double* __restrict__ tbuf)
{
  int s = blockIdx.x * 256 + threadIdx.x;
  int ch = s & 63;
  double r00, r01, r10, r11;
  mat_pow(a1[ch], a2[ch], LBLK * SEG_LEN, r00, r01, r10, r11);
  const double2* sb = (const double2*)sbuf;
  double2* tb = (double2*)tbuf;
  double y1 = 0.0, y2 = 0.0;
  for (int seg = 0; seg < NSEG; ++seg) {
    tb[(size_t)seg * 1024 + s] = make_double2(y1, y2);
    double2 f = sb[(size_t)seg * 1024 + s];
    double n1 = r00 * y1 + r01 * y2 + f.x;
    double n2 = r10 * y1 + r11 * y2 + f.y;
    y1 = n1; y2 = n2;
  }
}

// Pass 2c: expand segments 10..20 into per-block states for k in [250,500].
__global__ __launch_bounds__(64) void pass2c(
    const double* __restrict__ a1, const double* __restrict__ a2,
    const double* __restrict__ fbuf, const double* __restrict__ tbuf,
    double* __restrict__ ibuf)
{
  int seg = 10 + (blockIdx.x >> 4);
  int s = ((blockIdx.x & 15) << 6) + threadIdx.x;
  int ch = s & 63;
  double r00, r01, r10, r11;
  mat_pow(a1[ch], a2[ch], LBLK, r00, r01, r10, r11);
  const double2* fb = (const double2*)fbuf;
  double2* ib = (double2*)ibuf;
  double2 v = ((const double2*)tbuf)[(size_t)seg * 1024 + s];
  double y1 = v.x, y2 = v.y;
  for (int j = 0; j < SEG_LEN; ++j) {
    int k = seg * SEG_LEN + j;
    if (k >= IB_LO && k <= IB_HI)
      ib[(size_t)(k - IB_LO) * 1024 + s] = make_double2(y1, y2);
    double2 f = fb[(size_t)k * 1024 + s];
    double n1 = r00 * y1 + r01 * y2 + f.x;
    double n2 = r10 * y1 + r11 * y2 + f.y;
    y1 = n1; y2 = n2;
  }
}

// Pass 3: per (valid block k, batch b): f32 in-block recurrence from exact
// f64 block states -> f16 Y in LDS (double-buffered, 1 barrier/chunk) ->
// MFMA 16x16x32_f16 (W frags resident in VGPRs) -> tanh -> |p-t| reduce.
__global__ __launch_bounds__(256, 4) void pass3(
    const float* __restrict__ pred, const float* __restrict__ tgt,
    const float* __restrict__ cf, const _Float16* __restrict__ Wh,
    const double* __restrict__ ibuf, double* __restrict__ wsum)
{
  int k = K0 + blockIdx.x;
  int b = blockIdx.y;
  int tid = threadIdx.x;
  __shared__ __align__(16) _Float16 ys[2][64 * YSTR]; // [buf][col(2t+i)][128ch]
  __shared__ float xs[2][LBLK];
  __shared__ float red[4];

  // stage x for this block
  for (int idx = tid; idx < 2 * LBLK; idx += 256) {
    int ii = idx / LBLK, j = idx - ii * LBLK;
    const float* sig = (ii ? tgt : pred) + b * T_LEN;
    xs[ii][j] = sig[k * LBLK + j];
  }

  int g = tid >> 6, lane = tid & 63;
  int i = g >> 1, d = g & 1, ch = lane;
  int gu = __builtin_amdgcn_readfirstlane(g);
  int n0 = gu * 16;                 // wave's N-tile (16 cols = 8 t x 2 inputs)
  int lm = lane & 15, quad = lane >> 4;

  // W fragments resident in 64 VGPRs for the whole kernel
  half8 wf[4][4];
  #pragma unroll
  for (int m0 = 0; m0 < 4; ++m0) {
    #pragma unroll
    for (int k0 = 0; k0 < 4; ++k0)
      wf[m0][k0] = *(const half8*)(Wh + (m0 * 16 + lm) * 128 + k0 * 32 + quad * 8);
  }

  int s = (i * 8 + d * 4 + b) * 64 + ch;
  float A1 = cf[ch], A2 = cf[64 + ch], B0 = cf[128 + ch], IA2 = cf[192 + ch];
  double2 v = (d == 0)
      ? ((const double2*)ibuf)[(size_t)(k - IB_LO) * 1024 + s]   // (y[kL-1], y[kL-2])
      : ((const double2*)ibuf)[(size_t)(IB_HI - k) * 1024 + s];  // bwd state at t=kL
  float st0 = (float)v.x, st1 = (float)v.y;
  __syncthreads();

  float loss = 0.0f;
  for (int cc = 0; cc < NCHUNK; ++cc) {
    _Float16* yb = ys[cc & 1];
    // ---- recurrence phase (f32, wave-uniform direction) ----
    if (d == 0) {
      #pragma unroll
      for (int tt = 0; tt < CCH; ++tt) {
        float x = xs[i][cc * CCH + tt];
        float y = fmaf(-A1, st0, fmaf(-A2, st1, B0 * x));
        yb[(2 * tt + i) * YSTR + ch] = (_Float16)y;
        st1 = st0; st0 = y;
      }
    } else {
      #pragma unroll
      for (int tt = 0; tt < CCH; ++tt) {
        float x = xs[i][cc * CCH + tt];
        yb[(2 * tt + i) * YSTR + 64 + ch] = (_Float16)st0;
        float ym2 = (fmaf(-A1, st1, B0 * x) - st0) * IA2;
        st0 = st1; st1 = ym2;
      }
    }
    __syncthreads();   // only barrier: writes(buf) -> reads(buf); next write
                       // targets the other buffer, last read of which was
                       // before the previous barrier.

    // ---- MFMA phase: wave computes z[0..63][its 16 cols] ----
    const _Float16* yrow = &yb[(n0 + lm) * YSTR + quad * 8];
    half8 bf0 = *(const half8*)(yrow);
    half8 bf1 = *(const half8*)(yrow + 32);
    half8 bf2 = *(const half8*)(yrow + 64);
    half8 bf3 = *(const half8*)(yrow + 96);
    #pragma unroll
    for (int m0 = 0; m0 < 4; ++m0) {
      f32x4 c = {0.f, 0.f, 0.f, 0.f};
      c = __builtin_amdgcn_mfma_f32_16x16x32_f16(wf[m0][0], bf0, c, 0, 0, 0);
      c = __builtin_amdgcn_mfma_f32_16x16x32_f16(wf[m0][1], bf1, c, 0, 0, 0);
      c = __builtin_amdgcn_mfma_f32_16x16x32_f16(wf[m0][2], bf2, c, 0, 0, 0);
      c = __builtin_amdgcn_mfma_f32_16x16x32_f16(wf[m0][3], bf3, c, 0, 0, 0);
      #pragma unroll
      for (int r = 0; r < 4; ++r) {
        float vv = fast_tanh(c[r]);
        float p = __shfl_xor(vv, 1);   // partner col = other input, same t
        loss += fabsf(vv - p);
      }
    }
  }

  // block reduction -> one double atomic per workgroup
  #pragma unroll
  for (int off = 32; off > 0; off >>= 1) loss += __shfl_down(loss, off);
  if ((tid & 63) == 0) red[tid >> 6] = loss;
  __syncthreads();
  if (tid == 0) atomicAdd(wsum, (double)(red[0] + red[1] + red[2] + red[3]));
}

__global__ void finalize(const double* __restrict__ wsum, float* __restrict__ out) {
  out[0] = (float)(wsum[0] / DENOM);
}

extern "C" void kernel_launch(void* const* d_in, const int* in_sizes, int n_in,
                              void* d_out, int out_size, void* d_ws, size_t ws_size,
                              hipStream_t stream) {
  const float* pred = (const float*)d_in[0];
  const float* tgt  = (const float*)d_in[1];
  const float* W    = (const float*)d_in[5];
  float* out = (float*)d_out;

  double* base = (double*)d_ws;
  double* wsum = base;                              // [1] (pad to 8)
  double* ca1  = base + 8;                          // [64] f64
  double* ca2  = base + 72;                         // [64]
  double* cb0  = base + 136;                        // [64]
  float*  cf   = (float*)(base + 200);              // [256] f32: a1,a2,b0,1/a2
  _Float16* Wh = (_Float16*)(base + 328);           // [64*128] f16 (16 KB)
  double* fbuf = base + 2376;                       // [750][1024][2]
  double* ibuf = fbuf + (size_t)PBLK * 1024 * 2;    // [251][1024][2]
  double* sbuf = ibuf + (size_t)(IB_HI - IB_LO + 1) * 1024 * 2;  // [30][1024][2]
  double* tbuf = sbuf + (size_t)NSEG * 1024 * 2;    // [30][1024][2]

  canon<<<1, 256, 0, stream>>>(d_in[2], d_in[3], d_in[4], W,
                               ca1, ca2, cb0, cf, Wh, wsum);
  pass1<<<dim3(PBLK, 16), 64, 0, stream>>>(pred, tgt, cf, fbuf);
  pass2a<<<NSEG * 16, 64, 0, stream>>>(ca1, ca2, fbuf, sbuf);
  pass2b<<<dim3(4), 256, 0, stream>>>(ca1, ca2, sbuf, tbuf);
  pass2c<<<11 * 16, 64, 0, stream>>>(ca1, ca2, fbuf, tbuf, ibuf);
  pass3<<<dim3(NKV, BATCH), 256, 0, stream>>>(pred, tgt, cf, Wh, ibuf, wsum);
  finalize<<<1, 1, 0, stream>>>(wsum, out);
}

// Round 7
// 128.034 us; speedup vs baseline: 3.7939x; 1.0709x over previous
//
#include <hip/hip_runtime.h>

#define T_LEN 120000
#define LBLK 160          // samples per scan block (divides 40000)
#define PBLK 750          // number of scan blocks
#define SEG_LEN 25        // blocks per scan segment
#define NSEG 30           // segments (SEG_LEN*NSEG == PBLK)
#define CCH 32            // t-steps per pass3 chunk
#define NCHUNK (LBLK / CCH)
#define BATCH 4
#define K0 250            // first valid block (t = 40000)
#define NKV 250           // valid blocks (t in [40000, 80000))
#define DENOM 20480000.0  // 2 * 4 * 64 * 40000 (each |diff| counted twice)
#define YSTR 130          // halves per ys row: 128 ch + 2 pad (odd dword stride)

typedef _Float16 half8 __attribute__((ext_vector_type(8)));
typedef float f32x4 __attribute__((ext_vector_type(4)));

__device__ __forceinline__ float fast_tanh(float x) {
  float e = __expf(2.0f * x);
  return 1.0f - 2.0f / (e + 1.0f);
}

// Inline coefficient fetch: harness may store the reference's float64 arrays
// as f64 or f32. Detect via a2[0] = r^2 in (0.9,1.0) (f32-reinterpret fails
// the window). Data-stable -> graph-safe; no OOB either way.
__device__ __forceinline__ bool coeffs_are_f64(const void* a2p) {
  double probe = *(const double*)a2p;
  return probe > 0.9 && probe < 1.0;
}
__device__ __forceinline__ double coeff_d(const void* p, bool f64, int ch) {
  return f64 ? ((const double*)p)[ch] : (double)((const float*)p)[ch];
}

// state-transition matrix A^e for A = [[-a1,-a2],[1,0]] by repeated squaring
__device__ __forceinline__ void mat_pow(double A1, double A2, int e,
                                        double& r00, double& r01,
                                        double& r10, double& r11) {
  double m00 = -A1, m01 = -A2, m10 = 1.0, m11 = 0.0;
  r00 = 1.0; r01 = 0.0; r10 = 0.0; r11 = 1.0;
  while (e) {
    if (e & 1) {
      double t00 = r00 * m00 + r01 * m10, t01 = r00 * m01 + r01 * m11;
      double t10 = r10 * m00 + r11 * m10, t11 = r10 * m01 + r11 * m11;
      r00 = t00; r01 = t01; r10 = t10; r11 = t11;
    }
    e >>= 1;
    if (e) {
      double t00 = m00 * m00 + m01 * m10, t01 = m00 * m01 + m01 * m11;
      double t10 = m10 * m00 + m11 * m10, t11 = m10 * m01 + m11 * m11;
      m00 = t00; m01 = t01; m10 = t10; m11 = t11;
    }
  }
}

// Pass 1: per (row, block) forced response with zero initial state, f32.
// rows r: r = i*8 + d*4 + b  (i: 0=pred 1=target, d: 0=fwd 1=bwd, b: batch)
__global__ __launch_bounds__(64) void pass1(
    const float* __restrict__ pred, const float* __restrict__ tgt,
    const void* a1p, const void* a2p, const void* b0p,
    double* __restrict__ fbuf)
{
  int k = blockIdx.x, r = blockIdx.y;
  int i = r >> 3, d = (r >> 2) & 1, b = r & 3;
  const float* sig = (i ? tgt : pred) + b * T_LEN;
  __shared__ float xs[LBLK];
  int base = k * LBLK;
  for (int j = threadIdx.x; j < LBLK; j += 64)
    xs[j] = d ? sig[T_LEN - 1 - (base + j)] : sig[base + j];
  __syncthreads();
  int ch = threadIdx.x;
  bool f64 = coeffs_are_f64(a2p);
  float A1 = (float)coeff_d(a1p, f64, ch);
  float A2 = (float)coeff_d(a2p, f64, ch);
  float B0 = (float)coeff_d(b0p, f64, ch);
  float y1 = 0.0f, y2 = 0.0f;
  for (int j = 0; j < LBLK; ++j) {
    float y = fmaf(-A1, y1, fmaf(-A2, y2, B0 * xs[j]));
    y2 = y1; y1 = y;
  }
  int s = r * 64 + ch;
  ((double2*)fbuf)[(size_t)k * 1024 + s] = make_double2((double)y1, (double)y2);
}

// Pass 2a: per-segment aggregate (forced response of 25 blocks, zero init), f64.
__global__ __launch_bounds__(64) void pass2a(
    const void* a1p, const void* a2p,
    const double* __restrict__ fbuf, double* __restrict__ sbuf)
{
  int seg = blockIdx.x >> 4;
  int s = ((blockIdx.x & 15) << 6) + threadIdx.x;
  int ch = s & 63;
  bool f64 = coeffs_are_f64(a2p);
  double r00, r01, r10, r11;
  mat_pow(coeff_d(a1p, f64, ch), coeff_d(a2p, f64, ch), LBLK, r00, r01, r10, r11);
  const double2* fb = (const double2*)fbuf;
  double y1 = 0.0, y2 = 0.0;
  for (int jj = 0; jj < SEG_LEN / 5; ++jj) {
    size_t kb = (size_t)(seg * SEG_LEN + jj * 5) * 1024 + s;
    double2 f0 = fb[kb], f1 = fb[kb + 1024], f2 = fb[kb + 2048],
            f3 = fb[kb + 3072], f4 = fb[kb + 4096];
    double n1, n2;
    n1 = r00*y1 + r01*y2 + f0.x; n2 = r10*y1 + r11*y2 + f0.y; y1=n1; y2=n2;
    n1 = r00*y1 + r01*y2 + f1.x; n2 = r10*y1 + r11*y2 + f1.y; y1=n1; y2=n2;
    n1 = r00*y1 + r01*y2 + f2.x; n2 = r10*y1 + r11*y2 + f2.y; y1=n1; y2=n2;
    n1 = r00*y1 + r01*y2 + f3.x; n2 = r10*y1 + r11*y2 + f3.y; y1=n1; y2=n2;
    n1 = r00*y1 + r01*y2 + f4.x; n2 = r10*y1 + r11*y2 + f4.y; y1=n1; y2=n2;
  }
  ((double2*)sbuf)[(size_t)seg * 1024 + s] = make_double2(y1, y2);
}

// Pass 2b: serial scan over the 30 segment aggregates -> segment-start states.
// All loads prefetched (state-independent) -> one latency per 15-batch.
__global__ __launch_bounds__(256) void pass2b(
    const void* a1p, const void* a2p,
    const double* __restrict__ sbuf, double* __restrict__ tbuf)
{
  int s = blockIdx.x * 256 + threadIdx.x;
  int ch = s & 63;
  bool f64 = coeffs_are_f64(a2p);
  double r00, r01, r10, r11;
  mat_pow(coeff_d(a1p, f64, ch), coeff_d(a2p, f64, ch), LBLK * SEG_LEN,
          r00, r01, r10, r11);
  const double2* sb = (const double2*)sbuf;
  double2* tb = (double2*)tbuf;
  double y1 = 0.0, y2 = 0.0;
  #pragma unroll 1
  for (int half = 0; half < 2; ++half) {
    int base = half * 15;
    double2 f[15];
    #pragma unroll
    for (int q = 0; q < 15; ++q) f[q] = sb[(size_t)(base + q) * 1024 + s];
    #pragma unroll
    for (int q = 0; q < 15; ++q) {
      tb[(size_t)(base + q) * 1024 + s] = make_double2(y1, y2);
      double n1 = r00 * y1 + r01 * y2 + f[q].x;
      double n2 = r10 * y1 + r11 * y2 + f[q].y;
      y1 = n1; y2 = n2;
    }
  }
}

// Pass 3: per (valid block k, batch b). Prologue: each wave reconstructs its
// exact f64 block-start state from tbuf[seg] + <=24 predicated f64 steps over
// prefetched fbuf (folded pass2c). Then f32 in-block recurrence -> f16 Y in
// LDS (double-buffered) -> MFMA 16x16x32_f16 -> tanh -> |p-t| reduce.
// x reads are wave-uniform (scalar loads) -> no xs staging.
__global__ __launch_bounds__(256, 4) void pass3(
    const float* __restrict__ pred, const float* __restrict__ tgt,
    const void* a1p, const void* a2p, const void* b0p,
    const float* __restrict__ W, const double* __restrict__ fbuf,
    const double* __restrict__ tbuf, double* __restrict__ wsum)
{
  int k = K0 + blockIdx.x;
  int b = blockIdx.y;
  int tid = threadIdx.x;
  __shared__ __align__(16) _Float16 ys[2][64 * YSTR]; // [buf][col(2t+i)][128ch]
  __shared__ float red[4];

  int g = tid >> 6, lane = tid & 63;
  int gu = __builtin_amdgcn_readfirstlane(g);   // wave-uniform wave id
  int iu = gu >> 1, du = gu & 1;                // uniform input / direction
  int ch = lane;
  int n0 = gu * 16;                 // wave's N-tile (16 cols = 8 t x 2 inputs)
  int lm = lane & 15, quad = lane >> 4;

  bool f64 = coeffs_are_f64(a2p);
  double A1d = coeff_d(a1p, f64, ch), A2d = coeff_d(a2p, f64, ch);
  double B0d = coeff_d(b0p, f64, ch);
  float A1 = (float)A1d, A2 = (float)A2d, B0 = (float)B0d;
  float IA2 = (float)(1.0 / A2d);

  // ---- prologue: exact f64 state for this wave's needed scan block ----
  int m = du ? (PBLK - k) : k;            // fwd: block k; bwd: block 750-k
  int seg = m / SEG_LEN, j = m - seg * SEG_LEN;   // wave-uniform
  int s = (iu * 8 + du * 4 + b) * 64 + ch;
  double r00, r01, r10, r11;
  mat_pow(A1d, A2d, LBLK, r00, r01, r10, r11);
  double2 v0 = ((const double2*)tbuf)[(size_t)seg * 1024 + s];
  double y1 = v0.x, y2 = v0.y;
  const double2* fb = (const double2*)fbuf + (size_t)(seg * SEG_LEN) * 1024 + s;
  #pragma unroll 1
  for (int bb = 0; bb < 24; bb += 8) {
    double2 f[8];
    #pragma unroll
    for (int q = 0; q < 8; ++q) f[q] = fb[(size_t)(bb + q) * 1024];
    #pragma unroll
    for (int q = 0; q < 8; ++q) {
      if (bb + q < j) {     // uniform predicate
        double n1 = r00 * y1 + r01 * y2 + f[q].x;
        double n2 = r10 * y1 + r11 * y2 + f[q].y;
        y1 = n1; y2 = n2;
      }
    }
  }
  float st0 = (float)y1, st1 = (float)y2;

  // ---- W fragments: convert f32 -> f16 in registers (wave's 16-row slices) ----
  half8 wf[4][4];
  #pragma unroll
  for (int m0 = 0; m0 < 4; ++m0) {
    #pragma unroll
    for (int k0 = 0; k0 < 4; ++k0) {
      const float* wp = W + (m0 * 16 + lm) * 128 + k0 * 32 + quad * 8;
      float4 wa = *(const float4*)wp, wb = *(const float4*)(wp + 4);
      half8 h;
      h[0] = (_Float16)wa.x; h[1] = (_Float16)wa.y;
      h[2] = (_Float16)wa.z; h[3] = (_Float16)wa.w;
      h[4] = (_Float16)wb.x; h[5] = (_Float16)wb.y;
      h[6] = (_Float16)wb.z; h[7] = (_Float16)wb.w;
      wf[m0][k0] = h;
    }
  }

  // wave-uniform x pointer -> scalar loads
  const float* xp = (iu ? tgt : pred) + b * T_LEN + k * LBLK;

  float loss = 0.0f;
  for (int cc = 0; cc < NCHUNK; ++cc) {
    _Float16* yb = ys[cc & 1];
    // ---- recurrence phase (f32, uniform direction, scalar x) ----
    if (du == 0) {
      #pragma unroll
      for (int tt = 0; tt < CCH; ++tt) {
        float x = xp[cc * CCH + tt];
        float y = fmaf(-A1, st0, fmaf(-A2, st1, B0 * x));
        yb[(2 * tt + iu) * YSTR + ch] = (_Float16)y;
        st1 = st0; st0 = y;
      }
    } else {
      #pragma unroll
      for (int tt = 0; tt < CCH; ++tt) {
        float x = xp[cc * CCH + tt];
        yb[(2 * tt + iu) * YSTR + 64 + ch] = (_Float16)st0;
        float ym2 = (fmaf(-A1, st1, B0 * x) - st0) * IA2;
        st0 = st1; st1 = ym2;
      }
    }
    __syncthreads();   // writes(buf) -> reads(buf); next writes hit other buf

    // ---- MFMA phase: wave computes z[0..63][its 16 cols] ----
    const _Float16* yrow = &yb[(n0 + lm) * YSTR + quad * 8];
    half8 bf0 = *(const half8*)(yrow);
    half8 bf1 = *(const half8*)(yrow + 32);
    half8 bf2 = *(const half8*)(yrow + 64);
    half8 bf3 = *(const half8*)(yrow + 96);
    #pragma unroll
    for (int m0 = 0; m0 < 4; ++m0) {
      f32x4 c = {0.f, 0.f, 0.f, 0.f};
      c = __builtin_amdgcn_mfma_f32_16x16x32_f16(wf[m0][0], bf0, c, 0, 0, 0);
      c = __builtin_amdgcn_mfma_f32_16x16x32_f16(wf[m0][1], bf1, c, 0, 0, 0);
      c = __builtin_amdgcn_mfma_f32_16x16x32_f16(wf[m0][2], bf2, c, 0, 0, 0);
      c = __builtin_amdgcn_mfma_f32_16x16x32_f16(wf[m0][3], bf3, c, 0, 0, 0);
      #pragma unroll
      for (int r = 0; r < 4; ++r) {
        float vv = fast_tanh(c[r]);
        float p = __shfl_xor(vv, 1);   // partner col = other input, same t
        loss += fabsf(vv - p);
      }
    }
  }

  // block reduction -> one double atomic per workgroup
  #pragma unroll
  for (int off = 32; off > 0; off >>= 1) loss += __shfl_down(loss, off);
  if ((tid & 63) == 0) red[tid >> 6] = loss;
  __syncthreads();
  if (tid == 0) atomicAdd(wsum, (double)(red[0] + red[1] + red[2] + red[3]));
}

__global__ void finalize(const double* __restrict__ wsum, float* __restrict__ out) {
  out[0] = (float)(wsum[0] / DENOM);
}

extern "C" void kernel_launch(void* const* d_in, const int* in_sizes, int n_in,
                              void* d_out, int out_size, void* d_ws, size_t ws_size,
                              hipStream_t stream) {
  const float* pred = (const float*)d_in[0];
  const float* tgt  = (const float*)d_in[1];
  const void* a1p = d_in[2];
  const void* a2p = d_in[3];
  const void* b0p = d_in[4];
  const float* W  = (const float*)d_in[5];
  float* out = (float*)d_out;

  double* base = (double*)d_ws;
  double* wsum = base;                              // [1] (padded to 8)
  double* fbuf = base + 8;                          // [750][1024][2]
  double* sbuf = fbuf + (size_t)PBLK * 1024 * 2;    // [30][1024][2]
  double* tbuf = sbuf + (size_t)NSEG * 1024 * 2;    // [30][1024][2]

  hipMemsetAsync(wsum, 0, sizeof(double), stream);
  pass1<<<dim3(PBLK, 16), 64, 0, stream>>>(pred, tgt, a1p, a2p, b0p, fbuf);
  pass2a<<<NSEG * 16, 64, 0, stream>>>(a1p, a2p, fbuf, sbuf);
  pass2b<<<dim3(4), 256, 0, stream>>>(a1p, a2p, sbuf, tbuf);
  pass3<<<dim3(NKV, BATCH), 256, 0, stream>>>(pred, tgt, a1p, a2p, b0p,
                                              W, fbuf, tbuf, wsum);
  finalize<<<1, 1, 0, stream>>>(wsum, out);
}